// Round 8
// baseline (224.278 us; speedup 1.0000x reference)
//
#include <hip/hip_runtime.h>
#include <hip/hip_fp16.h>

#define N_NODES   100000
#define N_EDGES   3200000
#define N_FEAT    128
#define HIDDEN    16
#define MLP_H     100
#define N_CLASSES 12
#define N_GRAPHS  512
#define NBLK      391            // ceil(N_NODES/256)
#define BNODES    512            // nodes per bucket (dst>>9)
#define NBUCK     196            // ceil(N_NODES/512)
#define BCAP      18240          // bucket capacity (mean 16384 + 14.5 sigma), %16==0
#define CPAD      16             // counter padding (ints) -> 1 counter / 64B
#define RING      64             // LDS ring slots per bucket in kBin

// ---- init: gcursor[b] = b*BCAP ; pooled = 0 -------------------------------
__global__ __launch_bounds__(256) void kInit(int* __restrict__ gcursor,
                                             float* __restrict__ pooled) {
    int t = blockIdx.x * 256 + threadIdx.x;            // grid 32*256 = 8192
    if (t < NBUCK) gcursor[t * CPAD] = t * BCAP;
    if (t < N_GRAPHS * HIDDEN) pooled[t] = 0.f;
}

// ---- LDS-staged binning into fixed-capacity buckets (single-writer 64B) ---
__global__ __launch_bounds__(512) void kBin(const int* __restrict__ src,
                                            const int* __restrict__ dst,
                                            int* __restrict__ gcursor,
                                            int* __restrict__ pairs) {
    __shared__ int ring[NBUCK * RING];   // 50176 B
    __shared__ int cnt[NBUCK];
    __shared__ int fl[NBUCK];
    int t = threadIdx.x;
    for (int i = t; i < NBUCK; i += 512) { cnt[i] = 0; fl[i] = 0; }
    __syncthreads();
    const int batch = 512 * 4;                       // 2048 edges per block-iter
    for (int base = blockIdx.x * batch; base < N_EDGES;
         base += gridDim.x * batch) {
        int e0 = base + t * 4;
        if (e0 < N_EDGES) {                          // N_EDGES % 4 == 0
            int4 d4 = *(const int4*)&dst[e0];
            int4 s4 = *(const int4*)&src[e0];
            int dd[4] = {d4.x, d4.y, d4.z, d4.w};
            int ss[4] = {s4.x, s4.y, s4.z, s4.w};
#pragma unroll
            for (int k = 0; k < 4; ++k) {
                int b = dd[k] >> 9;
                int p = atomicAdd(&cnt[b], 1);
                ring[b * RING + (p & (RING - 1))] = (ss[k] << 9) | (dd[k] & 511);
            }
        }
        __syncthreads();
        if (t < NBUCK) {
            while (cnt[t] - fl[t] >= 16) {
                int start = fl[t];
                int gpos = atomicAdd(&gcursor[t * CPAD], 16);
                int rbase = t * RING + (start & (RING - 1)); // 16-aligned, no wrap
                const int4* rp = (const int4*)&ring[rbase];
                int4* gp = (int4*)&pairs[gpos];              // gpos % 16 == 0
                gp[0] = rp[0]; gp[1] = rp[1]; gp[2] = rp[2]; gp[3] = rp[3];
                fl[t] = start + 16;
            }
        }
        __syncthreads();
    }
    if (t < NBUCK) {
        int pending = cnt[t] - fl[t];
        if (pending > 0) {
            int gpos = atomicAdd(&gcursor[t * CPAD], pending);
            for (int k = 0; k < pending; ++k)
                pairs[gpos + k] = ring[t * RING + ((fl[t] + k) & (RING - 1))];
        }
    }
}

// ---- per-bucket: stage to LDS, counting-sort IN PLACE -> csr(byteoff) -----
__global__ __launch_bounds__(512) void kBuild(const int* __restrict__ gcursor,
                                              int* __restrict__ pairs,
                                              int* __restrict__ off,
                                              int* __restrict__ dcnt,
                                              float* __restrict__ dinv) {
    __shared__ int lp[BCAP];             // 72960 B
    __shared__ int hist[BNODES];
    __shared__ int sc[BNODES];
    __shared__ int lcur[BNODES];
    int b = blockIdx.x, t = threadIdx.x;
    int base = b * BCAP;
    int cnt = gcursor[b * CPAD] - base;
    for (int i = t; i < cnt; i += 512) lp[i] = pairs[base + i];
    hist[t] = 0;
    __syncthreads();
    for (int i = t; i < cnt; i += 512) atomicAdd(&hist[lp[i] & 511], 1);
    __syncthreads();
    sc[t] = hist[t];
    __syncthreads();
    for (int s = 1; s < 512; s <<= 1) {
        int a = (t >= s) ? sc[t - s] : 0;
        __syncthreads();
        sc[t] += a;
        __syncthreads();
    }
    int g = b * BNODES + t;
    int excl = base + sc[t] - hist[t];
    lcur[t] = excl;
    if (g < N_NODES) {
        off[g]  = excl;
        dcnt[g] = hist[t];
        dinv[g] = rsqrtf((float)hist[t] + 1.0f);  // +1 = self loop
    }
    __syncthreads();
    for (int i = t; i < cnt; i += 512) {
        int v = lp[i];
        int pos = atomicAdd(&lcur[v & 511], 1);
        pairs[pos] = (v >> 9) << 5;      // csr = byte offset of src row (fp16)
    }
}

// ---------------- hp16 = fp16( (x @ W1) * dinv[n] ) ------------------------
__global__ __launch_bounds__(256) void kGemm1(const float* __restrict__ x,
                                              const float* __restrict__ W1,
                                              const float* __restrict__ dinv,
                                              __half* __restrict__ hp16) {
    __shared__ float Ws[N_FEAT * HIDDEN];  // 8 KB
    for (int t = threadIdx.x; t < N_FEAT * HIDDEN; t += 256) Ws[t] = W1[t];
    __syncthreads();
    int n = blockIdx.x * 256 + threadIdx.x;
    if (n >= N_NODES) return;

    float acc[HIDDEN];
#pragma unroll
    for (int j = 0; j < HIDDEN; ++j) acc[j] = 0.f;

    const float4* xr = (const float4*)(x + (size_t)n * N_FEAT);
#pragma unroll 4
    for (int k4 = 0; k4 < N_FEAT / 4; ++k4) {
        float4 v = xr[k4];
        float xk[4] = {v.x, v.y, v.z, v.w};
#pragma unroll
        for (int kk = 0; kk < 4; ++kk) {
            const float4* wrow = (const float4*)&Ws[(k4 * 4 + kk) * HIDDEN];
#pragma unroll
            for (int j4 = 0; j4 < 4; ++j4) {
                float4 wv = wrow[j4];
                acc[j4 * 4 + 0] += xk[kk] * wv.x;
                acc[j4 * 4 + 1] += xk[kk] * wv.y;
                acc[j4 * 4 + 2] += xk[kk] * wv.z;
                acc[j4 * 4 + 3] += xk[kk] * wv.w;
            }
        }
    }
    float dv = dinv[n];
    union { __half2 h2[8]; int4 v4[2]; } u;
#pragma unroll
    for (int j2 = 0; j2 < 8; ++j2)
        u.h2[j2] = __floats2half2_rn(acc[2 * j2] * dv, acc[2 * j2 + 1] * dv);
    int4* hr = (int4*)(hp16 + (size_t)n * HIDDEN);
    hr[0] = u.v4[0];
    hr[1] = u.v4[1];
}

// ---- wave-per-node CSR gather-aggregate (fp16), 4 edge-slots x 16 feats ---
// aggval_j = (hp[n][j] + sum_s hp[s][j]) * dinv[n]
// MODE 1: out16 = fp16( dinv[n] * sum_k relu(aggval_k+b1[k])*W2[k][j] )
// MODE 0: val = relu(aggval_j + b2[j]); block pool over 16 nodes -> pooled
template <int MODE>
__global__ __launch_bounds__(MODE == 0 ? 1024 : 256, MODE == 0 ? 2 : 4)
void kAgg(const __half* __restrict__ hp, const float* __restrict__ dinv,
          const int* __restrict__ off, const int* __restrict__ dcnt,
          const int* __restrict__ csr, const float* __restrict__ W2,
          const float* __restrict__ bias, __half* __restrict__ out16,
          const int* __restrict__ batch, float* __restrict__ pooled) {
    __shared__ float W2s[HIDDEN * HIDDEN];
    __shared__ float bs[HIDDEN];
    __shared__ float red[256];
    __shared__ int sseg[2];
    constexpr int NW = (MODE == 0) ? 16 : 4;   // nodes (waves) per block
    int t = threadIdx.x;
    if (MODE == 1 && t < 256) W2s[t] = W2[t];
    if (t < HIDDEN) bs[t] = bias[t];
    int n0 = blockIdx.x * NW;
    if (MODE == 0) {
        if (t == 0) sseg[0] = batch[n0];
        if (t == 1) sseg[1] = batch[n0 + 15];
    }
    __syncthreads();

    int lane = t & 63;
    int slot = lane >> 4;                     // 0..3 edge slot
    int j = lane & 15;                        // feature
    int n = n0 + (t >> 6);                    // grid covers N_NODES exactly
    int beg = off[n];
    int deg = dcnt[n];
    const char* hpc = (const char*)hp;
    int jb = j << 1;
    float acc = 0.f;
    for (int cur = 0; cur < deg; cur += 64) {
        int nn = deg - cur; if (nn > 64) nn = 64;
        int pv = (lane < nn) ? csr[beg + cur + lane] : 0;   // byte offsets
        int nb = nn >> 2;
        int bat = 0;
        for (; bat + 8 <= nb; bat += 8) {
            float f[8];
#pragma unroll
            for (int q = 0; q < 8; ++q) {
                int sb = __shfl(pv, ((bat + q) << 2) | slot, 64);
                f[q] = __half2float(*(const __half*)(hpc + sb + jb));
            }
#pragma unroll
            for (int q = 0; q < 8; ++q) acc += f[q];
        }
        for (; bat < nb; ++bat) {
            int sb = __shfl(pv, (bat << 2) | slot, 64);
            acc += __half2float(*(const __half*)(hpc + sb + jb));
        }
        int rem = nn & 3;
        if (rem) {
            int sb = __shfl(pv, (nb << 2) | slot, 64);
            if (slot < rem)
                acc += __half2float(*(const __half*)(hpc + sb + jb));
        }
    }
    acc += __shfl_xor(acc, 16, 64);           // combine 4 slots
    acc += __shfl_xor(acc, 32, 64);
    acc += __half2float(hp[(size_t)n * HIDDEN + j]);   // self loop
    float dv = dinv[n];
    if (MODE == 1) {
        float tt = fmaxf(acc * dv + bs[j], 0.f);
        float o = 0.f;
#pragma unroll
        for (int k = 0; k < 16; ++k)
            o += __shfl(tt, k, 16) * W2s[k * HIDDEN + j];
        if (slot == 0)
            out16[(size_t)n * HIDDEN + j] = __float2half_rn(o * dv);
    } else {
        float val = fmaxf(acc * dv + bs[j], 0.f);
        if (slot == 0) red[(t >> 6) * 16 + j] = val;
        __syncthreads();
        if (sseg[0] == sseg[1]) {              // 16 nodes in one graph (common)
            if (t < 128) red[t] += red[t + 128];
            __syncthreads();
            if (t < 64) red[t] += red[t + 64];
            __syncthreads();
            if (t < 32) red[t] += red[t + 32];
            __syncthreads();
            if (t < 16)
                unsafeAtomicAdd(&pooled[(size_t)sseg[0] * HIDDEN + t],
                                red[t] + red[t + 16]);
        } else {
            if (t < 256)
                unsafeAtomicAdd(
                    &pooled[(size_t)batch[n0 + (t >> 4)] * HIDDEN + (t & 15)],
                    red[t]);
        }
    }
}

// ------- g=relu(pooled); g1=relu(g@lw1+lb1); out=g1@lw2+lb2 ----------------
__global__ __launch_bounds__(64) void kMlp(const float* __restrict__ pooled,
                                           const float* __restrict__ lw1,
                                           const float* __restrict__ lb1,
                                           const float* __restrict__ lw2,
                                           const float* __restrict__ lb2,
                                           float* __restrict__ out) {
    int g = blockIdx.x * 64 + threadIdx.x;
    if (g >= N_GRAPHS) return;
    float gv[HIDDEN];
#pragma unroll
    for (int k = 0; k < HIDDEN; ++k)
        gv[k] = fmaxf(pooled[(size_t)g * HIDDEN + k], 0.f);
    float o[N_CLASSES];
#pragma unroll
    for (int c = 0; c < N_CLASSES; ++c) o[c] = lb2[c];
    for (int j = 0; j < MLP_H; ++j) {
        float s = lb1[j];
#pragma unroll
        for (int k = 0; k < HIDDEN; ++k) s += gv[k] * lw1[k * MLP_H + j];
        s = fmaxf(s, 0.f);
#pragma unroll
        for (int c = 0; c < N_CLASSES; ++c) o[c] += s * lw2[j * N_CLASSES + c];
    }
#pragma unroll
    for (int c = 0; c < N_CLASSES; ++c) out[(size_t)g * N_CLASSES + c] = o[c];
}

extern "C" void kernel_launch(void* const* d_in, const int* in_sizes, int n_in,
                              void* d_out, int out_size, void* d_ws,
                              size_t ws_size, hipStream_t stream) {
    const float* x     = (const float*)d_in[0];
    const int*   ei    = (const int*)d_in[1];
    const int*   batch = (const int*)d_in[2];
    const float* W1    = (const float*)d_in[3];
    const float* b1    = (const float*)d_in[4];
    const float* W2    = (const float*)d_in[5];
    const float* b2    = (const float*)d_in[6];
    const float* lw1   = (const float*)d_in[7];
    const float* lb1   = (const float*)d_in[8];
    const float* lw2   = (const float*)d_in[9];
    const float* lb2   = (const float*)d_in[10];
    float* out = (float*)d_out;

    const int* src = ei;
    const int* dst = ei + N_EDGES;

    // workspace layout (bytes) — total 21,949,312
    char*   ws      = (char*)d_ws;
    int*    gcursor = (int*)(ws + 0);           // 12544 -> 16384
    float*  dinv    = (float*)(ws + 16384);     // 400000
    int*    off     = (int*)(ws + 416384);      // 400000
    int*    dcnt    = (int*)(ws + 816384);      // 400000
    int*    pairs   = (int*)(ws + 1216384);     // 196*18240*4 = 14300160 (=csr)
    __half* hp16    = (__half*)(ws + 15516544); // 3200000
    __half* hp2_16  = (__half*)(ws + 18716544); // 3200000
    float*  pooled  = (float*)(ws + 21916544);  // 32768

    kInit<<<32, 256, 0, stream>>>(gcursor, pooled);
    kBin<<<128, 512, 0, stream>>>(src, dst, gcursor, pairs);
    kBuild<<<NBUCK, 512, 0, stream>>>(gcursor, pairs, off, dcnt, dinv);

    kGemm1<<<NBLK, 256, 0, stream>>>(x, W1, dinv, hp16);
    // layer1 aggregate + layer2 transform fused -> hp2_16  (4 nodes/block)
    kAgg<1><<<N_NODES / 4, 256, 0, stream>>>(hp16, dinv, off, dcnt, pairs,
                                             W2, b1, hp2_16, nullptr, nullptr);
    // layer2 aggregate + relu(+b2) + fused pool -> pooled  (16 nodes/block)
    kAgg<0><<<N_NODES / 16, 1024, 0, stream>>>(hp2_16, dinv, off, dcnt, pairs,
                                               nullptr, b2, nullptr, batch,
                                               pooled);
    kMlp<<<(N_GRAPHS + 63) / 64, 64, 0, stream>>>(pooled, lw1, lb1, lw2, lb2, out);
}